// Round 1
// baseline (11363.652 us; speedup 1.0000x reference)
//
#include <hip/hip_runtime.h>
#include <math.h>

// ---------------- problem constants ----------------
namespace {
constexpr int NB = 4;
constexpr int SEQ = 128;
constexpr int TH_ = 120;
constexpr int NSTEP = 8;
constexpr int DMODEL = 512;
constexpr int NHEAD = 8;
constexpr int DHEAD = 64;
constexpr int DFFN = 2048;
constexpr int DIN = 32;
constexpr int MROWS = NB*SEQ;   // 512 flattened rows
constexpr float SCALE_EMB = 22.627416997969522f; // sqrt(512)
constexpr float LN_EPS = 1e-5f;
constexpr float NEGF = -3.4028234663852886e38f;  // jnp.finfo(f32).min
constexpr float PE_C = -0.017988946039015984f;   // -ln(10000)/512
constexpr unsigned NBLK = 128;  // persistent grid: 128 blocks < 256 CUs -> co-resident
}

using short8 = __attribute__((ext_vector_type(8))) short;
using f32x4  = __attribute__((ext_vector_type(4))) float;

// ---------------- grid barrier state (device global; zeroed by init_misc each launch) ----
__device__ unsigned g_cnt = 0;

// ---------------- device helpers ----------------
__device__ __forceinline__ float wave_sum(float v){
#pragma unroll
  for(int off=32;off;off>>=1) v += __shfl_xor(v,off,64);
  return v;
}
__device__ __forceinline__ float blk_sum(float v, float* scr){
  v = wave_sum(v);
  __syncthreads();
  if((threadIdx.x&63)==0) scr[threadIdx.x>>6]=v;
  __syncthreads();
  return scr[0]+scr[1]+scr[2]+scr[3];
}
__device__ __forceinline__ float gelu_t(float x){
  float t = 0.7978845608028654f*(x + 0.044715f*x*x*x);
  return 0.5f*x*(1.0f + tanhf(t));
}
__device__ __forceinline__ float pe_val(int t, int d){
  float div = expf((float)(d & ~1) * PE_C);
  float a = (float)t * div;
  return (d & 1) ? cosf(a) : sinf(a);
}
__device__ __forceinline__ unsigned short f2b(float f){
  union { float f; unsigned u; } c; c.f = f;
  unsigned u = c.u + 0x7FFFu + ((c.u>>16)&1u);
  return (unsigned short)(u>>16);
}
__device__ __forceinline__ short8 pack8(const float* f){
  short8 s;
#pragma unroll
  for(int i=0;i<8;i++) s[i] = (short)f2b(f[i]);
  return s;
}

// monotone-counter grid barrier. All NBLK blocks call in lockstep (uniform control flow).
__device__ __forceinline__ void gsync(unsigned target){
  __syncthreads();                 // drains vmcnt -> block stores are in L2
  if(threadIdx.x==0){
    __hip_atomic_fetch_add(&g_cnt, 1u, __ATOMIC_ACQ_REL, __HIP_MEMORY_SCOPE_AGENT);
    while(__hip_atomic_load(&g_cnt, __ATOMIC_ACQUIRE, __HIP_MEMORY_SCOPE_AGENT) < target){
      __builtin_amdgcn_s_sleep(1);
    }
  }
  __syncthreads();
}

// ---------------- shared-memory union (one allocation reused by every stage) ----------
struct SmemG { unsigned short As[64][72]; unsigned short Bs[128][72]; };          // 27.6 KB
struct SmemA { float kv[SEQ][DHEAD]; float wsm[32][132]; float qs[32][68]; };     // 58.4 KB
struct SmemC { float raw[DMODEL]; float ctx[DMODEL]; float scr[4]; };             //  4.1 KB
struct SmemR { float cur[DIN]; float gs[DFFN]; float dscr[DIN]; };                //  8.4 KB
union alignas(16) SmemU { SmemG g; SmemA a; SmemC c; SmemR r; };

// ---------------- one-time: convert all weights to bf16 ----------------
__global__ __launch_bounds__(256) void conv_w(const float* __restrict__ Wq,
                                              const float* __restrict__ Wk,
                                              const float* __restrict__ Wv,
                                              const float* __restrict__ Wo,
                                              const float* __restrict__ W1,
                                              const float* __restrict__ W2,
                                              unsigned short* __restrict__ dst){
  size_t base = ((size_t)blockIdx.x*256 + threadIdx.x)*8;
  if(base >= 12582912u) return;
  const float* src; size_t off;
  if(base < 1048576u){ src=Wq; off=base; }
  else if(base < 2097152u){ src=Wk; off=base-1048576u; }
  else if(base < 3145728u){ src=Wv; off=base-2097152u; }
  else if(base < 4194304u){ src=Wo; off=base-3145728u; }
  else if(base < 8388608u){ src=W1; off=base-4194304u; }
  else { src=W2; off=base-8388608u; }
  float4 a = *(const float4*)(src+off);
  float4 b = *(const float4*)(src+off+4);
  float f[8] = {a.x,a.y,a.z,a.w,b.x,b.y,b.z,b.w};
  *(short8*)(dst + base) = pack8(f);
}

// ---------------- h0 init (fp32 + bf16) ----------------
__global__ __launch_bounds__(256) void init_h0(const float* __restrict__ hist,
                                               const float* __restrict__ W_emb,
                                               const float* __restrict__ b_emb,
                                               float* __restrict__ h0,
                                               unsigned short* __restrict__ h0b){
  int bt = blockIdx.x;
  int b = bt >> 7, t = bt & 127;
  __shared__ float x[DIN];
  if(threadIdx.x < DIN)
    x[threadIdx.x] = (t < TH_) ? hist[((size_t)b*TH_ + t)*DIN + threadIdx.x] : 0.f;
  __syncthreads();
  for(int d = threadIdx.x; d < DMODEL; d += 256){
    float s = 0.f;
#pragma unroll 8
    for(int i=0;i<DIN;i++) s += W_emb[d*DIN+i]*x[i];
    float v = SCALE_EMB*(s + b_emb[d]) + pe_val(t,d);
    h0[(size_t)bt*DMODEL + d] = v;
    h0b[(size_t)bt*DMODEL + d] = f2b(v);
  }
}

// ---------------- M1 / cb1 / cur_x init (+ barrier reset) ----------------
__global__ __launch_bounds__(256) void init_misc(const float* __restrict__ Wr1,
                                                 const float* __restrict__ W_emb,
                                                 const float* __restrict__ b_emb,
                                                 const float* __restrict__ br1,
                                                 const float* __restrict__ hist,
                                                 float* __restrict__ M1,
                                                 float* __restrict__ cb1,
                                                 float* __restrict__ cur_x){
  if(blockIdx.x==0 && threadIdx.x==255) g_cnt = 0u;   // reset grid barrier each replay
  __shared__ float row[DMODEL];
  int j0 = blockIdx.x*8;
  for(int jj=0;jj<8;jj++){
    int j = j0+jj;
    for(int k=threadIdx.x;k<DMODEL;k+=256) row[k] = Wr1[(size_t)j*1024 + k];
    __syncthreads();
    if(threadIdx.x < DIN){
      int i = threadIdx.x; float s = 0.f;
      for(int k=0;k<DMODEL;k++) s += row[k]*W_emb[k*DIN+i];
      M1[j*DIN+i] = SCALE_EMB*s;
    } else if(threadIdx.x == DIN){
      float s=0.f;
      for(int k=0;k<DMODEL;k++) s += row[k]*b_emb[k];
      cb1[j] = br1[j] + SCALE_EMB*s;
    }
    __syncthreads();
  }
  if(blockIdx.x==0 && threadIdx.x<NB*DIN){
    int b = threadIdx.x>>5, i = threadIdx.x&31;
    cur_x[b*DIN+i] = hist[((size_t)b*TH_ + (TH_-1))*DIN + i];
  }
}

// ---------------- stage bodies (verbatim ports of the former kernels) ----------------

// LN pass: Y = LN(X)*g+b (fp32) and bf16 copy.  vb in [0,128); wave = one row.
__device__ __forceinline__ void lnpass_body(int vb,
                                            const float* __restrict__ X,
                                            const float* __restrict__ g,
                                            const float* __restrict__ bta,
                                            float* __restrict__ Y,
                                            unsigned short* __restrict__ Yb){
  int row = vb*4 + (threadIdx.x>>6);
  int l = threadIdx.x&63;
  const float* xp = X + (size_t)row*DMODEL + l*8;
  float4 x0 = *(const float4*)xp;
  float4 x1 = *(const float4*)(xp+4);
  float f[8] = {x0.x,x0.y,x0.z,x0.w,x1.x,x1.y,x1.z,x1.w};
  float s = 0.f;
#pragma unroll
  for(int i=0;i<8;i++) s += f[i];
  s = wave_sum(s);
  float mu = s*(1.f/DMODEL);
  float v = 0.f;
#pragma unroll
  for(int i=0;i<8;i++){ float d0=f[i]-mu; v += d0*d0; }
  v = wave_sum(v);
  float rs = rsqrtf(v*(1.f/DMODEL) + LN_EPS);
#pragma unroll
  for(int i=0;i<8;i++){
    int c = l*8+i;
    f[i] = (f[i]-mu)*rs*g[c] + bta[c];
  }
  float* yp = Y + (size_t)row*DMODEL + l*8;
  *(float4*)yp     = make_float4(f[0],f[1],f[2],f[3]);
  *(float4*)(yp+4) = make_float4(f[4],f[5],f[6],f[7]);
  *(short8*)(Yb + (size_t)row*DMODEL + l*8) = pack8(f);
}

// bf16 MFMA GEMM tile 64x128, 4 waves.  (bx,by) = former (blockIdx.x, blockIdx.y).
__device__ __forceinline__ void gemm_body(int bx, int by, SmemG& S,
    const unsigned short* __restrict__ A16, int Ka,
    const unsigned short* __restrict__ Wa,
    const unsigned short* __restrict__ Wb,
    const unsigned short* __restrict__ Wc,
    const float* __restrict__ bias, const float* __restrict__ resid,
    float* __restrict__ Cf, unsigned short* __restrict__ Cb,
    int c_rs, int c_mode, int act)
{
  int n0 = bx*128;
  int m0 = by*64;
  int tid = threadIdx.x, w = tid>>6, ln = tid&63;

  const unsigned short* Wsrc; int nrow0;
  if(c_mode==2){ int which = n0>>9; Wsrc = (which==0?Wa:(which==1?Wb:Wc)); nrow0 = n0&511; }
  else { Wsrc = Wa; nrow0 = n0; }

  f32x4 acc[4][2];
#pragma unroll
  for(int i=0;i<4;i++)
#pragma unroll
    for(int j=0;j<2;j++) acc[i][j] = (f32x4){0.f,0.f,0.f,0.f};

  int fr = ln&15, fq = (ln>>4)*8;
  int arow = tid>>2, akq = (tid&3)*16;
  int brow = tid>>1, bkq = (tid&1)*32;

  for(int k0=0;k0<Ka;k0+=64){
    const unsigned short* ap = A16 + (size_t)(m0+arow)*Ka + k0 + akq;
    short8 a0 = *(const short8*)ap;
    short8 a1 = *(const short8*)(ap+8);
    const unsigned short* bp = Wsrc + (size_t)(nrow0+brow)*Ka + k0 + bkq;
    short8 b0 = *(const short8*)bp;
    short8 b1 = *(const short8*)(bp+8);
    short8 b2 = *(const short8*)(bp+16);
    short8 b3 = *(const short8*)(bp+24);
    *(short8*)&S.As[arow][akq]   = a0;
    *(short8*)&S.As[arow][akq+8] = a1;
    *(short8*)&S.Bs[brow][bkq]    = b0;
    *(short8*)&S.Bs[brow][bkq+8]  = b1;
    *(short8*)&S.Bs[brow][bkq+16] = b2;
    *(short8*)&S.Bs[brow][bkq+24] = b3;
    __syncthreads();
    short8 af[4][2], bf[2][2];
#pragma unroll
    for(int kf=0;kf<2;kf++){
#pragma unroll
      for(int rt=0;rt<4;rt++) af[rt][kf] = *(const short8*)&S.As[rt*16 + fr][kf*32 + fq];
#pragma unroll
      for(int ct=0;ct<2;ct++) bf[ct][kf] = *(const short8*)&S.Bs[32*w + ct*16 + fr][kf*32 + fq];
    }
#pragma unroll
    for(int kf=0;kf<2;kf++)
#pragma unroll
      for(int rt=0;rt<4;rt++)
#pragma unroll
        for(int ct=0;ct<2;ct++)
          acc[rt][ct] = __builtin_amdgcn_mfma_f32_16x16x32_bf16(af[rt][kf], bf[ct][kf], acc[rt][ct], 0, 0, 0);
    __syncthreads();
  }

#pragma unroll
  for(int rt=0;rt<4;rt++){
#pragma unroll
    for(int ct=0;ct<2;ct++){
      int n = n0 + 32*w + ct*16 + fr;
#pragma unroll
      for(int r=0;r<4;r++){
        int row = m0 + rt*16 + (ln>>4)*4 + r;
        float v = acc[rt][ct][r];
        if(bias)  v += bias[n];
        if(resid) v += resid[(size_t)row*DMODEL + n];
        if(act==1) v = gelu_t(v);
        if(c_mode==0)      Cf[(size_t)row*c_rs + n] = v;
        else if(c_mode==1) Cb[(size_t)row*c_rs + n] = f2b(v);
        else {
          int which = n>>9, rem = n&511;
          int b = row>>7, t = row&127;
          Cf[(size_t)which*(MROWS*DMODEL) +
             ((size_t)(b*NHEAD + (rem>>6))*SEQ + t)*DHEAD + (rem&63)] = v;
        }
      }
    }
  }
}

// fused attention per (b,h); 32 rows per body call; writes bf16.
__device__ __forceinline__ void attn_body(int bx, int h, int b, SmemA& S,
                                          const float* __restrict__ qb,
                                          const float* __restrict__ kb,
                                          const float* __restrict__ vbuf,
                                          unsigned short* __restrict__ attb){
  int r0 = bx*32;
  const float* Kh = kb   + (size_t)(b*NHEAD+h)*SEQ*DHEAD;
  const float* Vh = vbuf + (size_t)(b*NHEAD+h)*SEQ*DHEAD;
  const float* Qh = qb   + (size_t)(b*NHEAD+h)*SEQ*DHEAD;
  int tid = threadIdx.x;
  int d = tid&63, rr = tid>>6;

  for(int k=rr;k<SEQ;k+=4) S.kv[k][d ^ (k&60)] = Kh[k*DHEAD + d];
  for(int r=rr;r<32;r+=4)  S.qs[r][d] = Qh[(size_t)(r0+r)*DHEAD + d];
  __syncthreads();

  { // logits: 2 rows x 8 keys per thread, float4 LDS reads
    int rp = tid>>4;
    int kg = tid&15;
    float acc[2][8];
#pragma unroll
    for(int i=0;i<2;i++)
#pragma unroll
      for(int kk=0;kk<8;kk++) acc[i][kk]=0.f;
#pragma unroll 4
    for(int d4=0;d4<16;d4++){
      float4 q0 = *(const float4*)&S.qs[2*rp][d4*4];
      float4 q1 = *(const float4*)&S.qs[2*rp+1][d4*4];
#pragma unroll
      for(int kk=0;kk<8;kk++){
        int k = 8*kg + kk;
        int off = (d4*4) ^ (k&60);
        float4 kv4 = *(const float4*)&S.kv[k][off];
        acc[0][kk] += q0.x*kv4.x + q0.y*kv4.y + q0.z*kv4.z + q0.w*kv4.w;
        acc[1][kk] += q1.x*kv4.x + q1.y*kv4.y + q1.z*kv4.z + q1.w*kv4.w;
      }
    }
#pragma unroll
    for(int i=0;i<2;i++){
      int t = r0 + 2*rp + i;
#pragma unroll
      for(int kk=0;kk<8;kk++){
        int k = 8*kg + kk;
        S.wsm[2*rp+i][k] = (k > t) ? acc[i][kk]*0.125f : NEGF;
      }
    }
  }
  __syncthreads();

  { // softmax per row (all-masked row -> uniform 1/128, faithful to jnp)
    int l2 = tid&63, wv = tid>>6;
    for(int r=wv;r<32;r+=4){
      float l0 = S.wsm[r][l2], l1 = S.wsm[r][l2+64];
      float m = fmaxf(l0,l1);
#pragma unroll
      for(int off=32;off;off>>=1) m = fmaxf(m, __shfl_xor(m,off,64));
      float e0 = expf(l0-m), e1 = expf(l1-m);
      float s = e0+e1;
      s = wave_sum(s);
      float inv = 1.f/s;
      S.wsm[r][l2] = e0*inv; S.wsm[r][l2+64] = e1*inv;
    }
  }
  __syncthreads();

  for(int k=rr;k<SEQ;k+=4) S.kv[k][d] = Vh[k*DHEAD + d];   // overwrite with V
  __syncthreads();

  { // out = w @ V, pack bf16
    int dq = (tid&15)*4, rg = tid>>4;
    for(int r=rg;r<32;r+=16){
      float4 acc2 = make_float4(0.f,0.f,0.f,0.f);
      for(int k=0;k<SEQ;k++){
        float w0 = S.wsm[r][k];
        float4 v = *(const float4*)&S.kv[k][dq];
        acc2.x += w0*v.x; acc2.y += w0*v.y; acc2.z += w0*v.z; acc2.w += w0*v.w;
      }
      int row = b*SEQ + r0 + r;
      unsigned short* op = attb + (size_t)row*DMODEL + h*DHEAD + dq;
      op[0]=f2b(acc2.x); op[1]=f2b(acc2.y); op[2]=f2b(acc2.z); op[3]=f2b(acc2.w);
    }
  }
}

// ctx = LN2_3(r2[ptr-1]); ctxt = Wr1b@ctx + cb1
__device__ __forceinline__ void ctx_body(int jx, int b, SmemC& S,
                                         const float* __restrict__ r2,
                                         const float* __restrict__ g2,
                                         const float* __restrict__ b2,
                                         const float* __restrict__ Wr1,
                                         const float* __restrict__ cb1,
                                         float* __restrict__ ctxt, int ptr){
  int j0 = jx*128;
  int tid = threadIdx.x;
  const float* rp = r2 + (size_t)(b*SEQ + ptr-1)*DMODEL;
  for(int k=tid;k<DMODEL;k+=256) S.raw[k]=rp[k];
  __syncthreads();
  float s = 0.f;
  for(int k=tid;k<DMODEL;k+=256) s += S.raw[k];
  s = blk_sum(s, S.scr);
  float mu = s/(float)DMODEL;
  float v = 0.f;
  for(int k=tid;k<DMODEL;k+=256){ float d0 = S.raw[k]-mu; v += d0*d0; }
  v = blk_sum(v, S.scr);
  float rs = rsqrtf(v/(float)DMODEL + LN_EPS);
  for(int k=tid;k<DMODEL;k+=256) S.ctx[k] = (S.raw[k]-mu)*rs*g2[k] + b2[k];
  __syncthreads();
  int wv = tid>>6, l2 = tid&63;
  for(int jj=wv;jj<128;jj+=4){
    int j = j0+jj;
    const float* wp = Wr1 + (size_t)j*1024 + 512;
    float acc = 0.f;
#pragma unroll
    for(int q=0;q<8;q++){ int k = l2 + 64*q; acc += wp[k]*S.ctx[k]; }
    acc = wave_sum(acc);
    if(l2==0) ctxt[b*DFFN + j] = acc + cb1[j];
  }
}

// fused refine (5 substeps) + finalize; one body call per batch.
__device__ __forceinline__ void refine_body(int b, SmemR& S,
                                            const float* __restrict__ M1,
                                            const float* __restrict__ ctxt,
                                            const float* __restrict__ Wr2,
                                            const float* __restrict__ br2,
                                            float* __restrict__ cur_x,
                                            const float* __restrict__ W_emb,
                                            const float* __restrict__ b_emb,
                                            float* __restrict__ out,
                                            float* __restrict__ h0,
                                            unsigned short* __restrict__ h0b,
                                            int s, int ptr){
  int tid = threadIdx.x;
  if(tid < DIN) S.cur[tid] = cur_x[b*DIN + tid];
  __syncthreads();
  for(int sub=0; sub<5; sub++){
    for(int jj=tid; jj<DFFN; jj+=256){
      float u = ctxt[b*DFFN + jj];
      const float* mp = M1 + (size_t)jj*DIN;
#pragma unroll
      for(int p=0;p<8;p++){
        float4 mv = *(const float4*)(mp + 4*p);
        u += mv.x*S.cur[4*p] + mv.y*S.cur[4*p+1] + mv.z*S.cur[4*p+2] + mv.w*S.cur[4*p+3];
      }
      S.gs[jj] = gelu_t(u);
    }
    __syncthreads();
    int w = tid>>6, l = tid&63;
#pragma unroll
    for(int q=0;q<8;q++){
      int i = w*8 + q;
      const float* wr = Wr2 + (size_t)i*DFFN;
      float a = 0.f;
#pragma unroll
      for(int p=0;p<8;p++){
        int j0 = p*256 + l*4;
        float4 wv = *(const float4*)(wr + j0);
        float4 gv = *(const float4*)&S.gs[j0];
        a += wv.x*gv.x + wv.y*gv.y + wv.z*gv.z + wv.w*gv.w;
      }
      a = wave_sum(a);
      if(l==0) S.dscr[i] = a;
    }
    __syncthreads();
    if(tid < DIN) S.cur[tid] += S.dscr[tid] + br2[tid];
    __syncthreads();
  }
  if(tid < DIN){
    out[(b*NSTEP + s)*DIN + tid] = S.cur[tid];
    cur_x[b*DIN + tid] = S.cur[tid];
  }
  __syncthreads();
  for(int d=tid; d<DMODEL; d+=256){
    float s2 = 0.f;
#pragma unroll 8
    for(int i=0;i<DIN;i++) s2 += W_emb[d*DIN+i]*S.cur[i];
    float v = SCALE_EMB*(s2 + b_emb[d]) + pe_val(ptr, d);
    size_t idx = (size_t)(b*SEQ + ptr)*DMODEL + d;
    h0[idx] = v;
    h0b[idx] = f2b(v);
  }
}

// ---------------- megakernel params ----------------
struct MegaP {
  const float *ln1g, *ln1b, *b1, *b2v, *ln2g, *ln2b, *Wr1, *W_emb, *b_emb, *Wr2, *br2;
  float *out;
  float *h0; unsigned short *h0b;
  float *r2, *hln, *hp; unsigned short *hpb;
  float *qb, *kb, *vb; unsigned short *attb, *hlnb, *fbuf16;
  float *r1;
  const unsigned short *Wq16, *Wk16, *Wv16, *Wo16, *W116, *W216;
  float *M1, *cb1, *ctxt, *cur_x;
};

// ---------------- the persistent megakernel: whole step loop, barriers replace launches ----
__global__ __launch_bounds__(256,1) void mega(MegaP p){
  __shared__ SmemU sm;
  const unsigned vbk = blockIdx.x;
  unsigned ep = 0;
#define GS() do{ ++ep; gsync(ep*NBLK); }while(0)

  for(int s=0;s<NSTEP;s++){
    int ptr = TH_ + s;
    for(int l=0;l<4;l++){
      const unsigned short* A16; const float* res1;
      if(l>0){
        lnpass_body(vbk, p.r2, p.ln2g+(l-1)*DMODEL, p.ln2b+(l-1)*DMODEL, p.hln, p.hlnb);
        GS();
        A16 = p.hlnb; res1 = p.hln;
      } else { A16 = p.h0b; res1 = p.h0; }

      // fused QKV: N=1536 -> qb/kb/vb scatter (former grid 12x8 = 96 blocks)
      if(vbk < 96)
        gemm_body((int)(vbk%12u), (int)(vbk/12u), sm.g, A16, DMODEL,
                  p.Wq16 + (size_t)l*262144, p.Wk16 + (size_t)l*262144, p.Wv16 + (size_t)l*262144,
                  nullptr, nullptr, p.qb, nullptr, 0, 2, 0);
      GS();

      // attention (former grid 4x8x4 = 128 blocks)
      attn_body((int)(vbk&3u), (int)((vbk>>2)&7u), (int)(vbk>>5), sm.a, p.qb, p.kb, p.vb, p.attb);
      GS();

      // Wo: att@Wo^T + resid -> r1 (former grid 4x8 = 32 blocks)
      if(vbk < 32)
        gemm_body((int)(vbk&3u), (int)(vbk>>2), sm.g, p.attb, DMODEL,
                  p.Wo16 + (size_t)l*262144, nullptr, nullptr,
                  nullptr, res1, p.r1, nullptr, DMODEL, 0, 0);
      GS();

      // LN1: r1 -> hp/hpb (128 blocks)
      lnpass_body(vbk, p.r1, p.ln1g+l*DMODEL, p.ln1b+l*DMODEL, p.hp, p.hpb);
      GS();

      // FF1: gelu(hp@W1^T + b1) -> fbuf bf16 (former grid 16x8 = 128 blocks)
      gemm_body((int)(vbk&15u), (int)(vbk>>4), sm.g, p.hpb, DMODEL,
                p.W116 + (size_t)l*1048576, nullptr, nullptr,
                p.b1 + l*DFFN, nullptr, nullptr, p.fbuf16, DFFN, 1, 1);
      GS();

      // FF2: fbuf@W2^T + b2 + hp -> r2 fp32 (former grid 4x8 = 32 blocks)
      if(vbk < 32)
        gemm_body((int)(vbk&3u), (int)(vbk>>2), sm.g, p.fbuf16, DFFN,
                  p.W216 + (size_t)l*1048576, nullptr, nullptr,
                  p.b2v + l*DMODEL, p.hp, p.r2, nullptr, DMODEL, 0, 0);
      GS();
    }

    // ctx (former grid 16x4 = 64 blocks)
    if(vbk < 64)
      ctx_body((int)(vbk&15u), (int)(vbk>>4), sm.c, p.r2,
               p.ln2g + 3*DMODEL, p.ln2b + 3*DMODEL, p.Wr1, p.cb1, p.ctxt, ptr);
    GS();

    // refine + finalize + write next h0 row (former grid 4 blocks)
    if(vbk < 4)
      refine_body((int)vbk, sm.r, p.M1, p.ctxt, p.Wr2, p.br2, p.cur_x,
                  p.W_emb, p.b_emb, p.out, p.h0, p.h0b, s, ptr);
    GS();
  }
#undef GS
}

// ---------------- host ----------------
extern "C" void kernel_launch(void* const* d_in, const int* in_sizes, int n_in,
                              void* d_out, int out_size, void* d_ws, size_t ws_size,
                              hipStream_t stream) {
  (void)in_sizes; (void)n_in; (void)out_size; (void)ws_size;
  const float* hist = (const float*)d_in[0];
  const float* W_emb= (const float*)d_in[2];
  const float* b_emb= (const float*)d_in[3];
  const float* Wq   = (const float*)d_in[4];
  const float* Wk   = (const float*)d_in[5];
  const float* Wv   = (const float*)d_in[6];
  const float* Wo   = (const float*)d_in[7];
  const float* ln1g = (const float*)d_in[8];
  const float* ln1b = (const float*)d_in[9];
  const float* W1   = (const float*)d_in[10];
  const float* b1   = (const float*)d_in[11];
  const float* W2   = (const float*)d_in[12];
  const float* b2v  = (const float*)d_in[13];
  const float* ln2g = (const float*)d_in[14];
  const float* ln2b = (const float*)d_in[15];
  const float* Wr1  = (const float*)d_in[16];
  const float* br1  = (const float*)d_in[17];
  const float* Wr2  = (const float*)d_in[18];
  const float* br2  = (const float*)d_in[19];
  float* out = (float*)d_out;
  float* ws  = (float*)d_ws;

  const size_t BTD = (size_t)MROWS*DMODEL;      // 262144 floats
  const size_t BTDH = BTD/2;                    // bf16 buffer in float units
  float* h0   = ws;
  unsigned short* h0b = (unsigned short*)(h0 + BTD);
  float* r2   = h0 + BTD + BTDH;
  float* hln  = r2 + BTD;
  float* hp   = hln + BTD;
  unsigned short* hpb = (unsigned short*)(hp + BTD);
  float* qb   = hp + BTD + BTDH;
  float* kb   = qb + BTD;
  float* vb   = kb + BTD;
  unsigned short* attb = (unsigned short*)(vb + BTD);
  unsigned short* hlnb = (unsigned short*)(vb + BTD + BTDH);
  unsigned short* fbuf16 = (unsigned short*)qb;   // [512][2048] bf16
  float* r1   = qb;                                // alias (qb dead when Wo writes)
  unsigned short* W16 = (unsigned short*)(qb + 4*BTD);
  float* after_w = qb + 4*BTD + 6291456;
  float* M1   = after_w;
  float* cb1  = M1 + (size_t)DFFN*DIN;
  float* ctxt = cb1 + DFFN;
  float* cur_x= ctxt + NB*DFFN;

  unsigned short* Wq16 = W16;
  unsigned short* Wk16 = W16 + 1048576;
  unsigned short* Wv16 = W16 + 2097152;
  unsigned short* Wo16 = W16 + 3145728;
  unsigned short* W116 = W16 + 4194304;
  unsigned short* W216 = W16 + 8388608;

  conv_w<<<dim3(6144),dim3(256),0,stream>>>(Wq,Wk,Wv,Wo,W1,W2,W16);
  init_h0<<<dim3(MROWS),dim3(256),0,stream>>>(hist,W_emb,b_emb,h0,h0b);
  init_misc<<<dim3(256),dim3(256),0,stream>>>(Wr1,W_emb,b_emb,br1,hist,M1,cb1,cur_x);

  MegaP p;
  p.ln1g=ln1g; p.ln1b=ln1b; p.b1=b1; p.b2v=b2v; p.ln2g=ln2g; p.ln2b=ln2b;
  p.Wr1=Wr1; p.W_emb=W_emb; p.b_emb=b_emb; p.Wr2=Wr2; p.br2=br2;
  p.out=out;
  p.h0=h0; p.h0b=h0b;
  p.r2=r2; p.hln=hln; p.hp=hp; p.hpb=hpb;
  p.qb=qb; p.kb=kb; p.vb=vb; p.attb=attb; p.hlnb=hlnb; p.fbuf16=fbuf16;
  p.r1=r1;
  p.Wq16=Wq16; p.Wk16=Wk16; p.Wv16=Wv16; p.Wo16=Wo16; p.W116=W116; p.W216=W216;
  p.M1=M1; p.cb1=cb1; p.ctxt=ctxt; p.cur_x=cur_x;

  mega<<<dim3(NBLK),dim3(256),0,stream>>>(p);
}

// Round 2
// 7659.663 us; speedup vs baseline: 1.4836x; 1.4836x over previous
//
#include <hip/hip_runtime.h>
#include <math.h>

// ---------------- problem constants ----------------
namespace {
constexpr int NB = 4;
constexpr int SEQ = 128;
constexpr int TH_ = 120;
constexpr int NSTEP = 8;
constexpr int DMODEL = 512;
constexpr int NHEAD = 8;
constexpr int DHEAD = 64;
constexpr int DFFN = 2048;
constexpr int DIN = 32;
constexpr int MROWS = NB*SEQ;   // 512 flattened rows
constexpr float SCALE_EMB = 22.627416997969522f; // sqrt(512)
constexpr float LN_EPS = 1e-5f;
constexpr float NEGF = -3.4028234663852886e38f;  // jnp.finfo(f32).min
constexpr float PE_C = -0.017988946039015984f;   // -ln(10000)/512
constexpr unsigned NBLK = 128;  // persistent grid: 128 blocks < 256 CUs -> co-resident
}

using short8 = __attribute__((ext_vector_type(8))) short;
using f32x4  = __attribute__((ext_vector_type(4))) float;

// ---------------- grid barrier state (device global; zeroed by init_misc each launch) ----
__device__ unsigned g_cnt = 0;

// ---------------- device helpers ----------------
__device__ __forceinline__ float wave_sum(float v){
#pragma unroll
  for(int off=32;off;off>>=1) v += __shfl_xor(v,off,64);
  return v;
}
__device__ __forceinline__ float blk_sum(float v, float* scr){
  v = wave_sum(v);
  __syncthreads();
  if((threadIdx.x&63)==0) scr[threadIdx.x>>6]=v;
  __syncthreads();
  return scr[0]+scr[1]+scr[2]+scr[3];
}
__device__ __forceinline__ float gelu_t(float x){
  float t = 0.7978845608028654f*(x + 0.044715f*x*x*x);
  return 0.5f*x*(1.0f + tanhf(t));
}
__device__ __forceinline__ float pe_val(int t, int d){
  float div = expf((float)(d & ~1) * PE_C);
  float a = (float)t * div;
  return (d & 1) ? cosf(a) : sinf(a);
}
__device__ __forceinline__ unsigned short f2b(float f){
  union { float f; unsigned u; } c; c.f = f;
  unsigned u = c.u + 0x7FFFu + ((c.u>>16)&1u);
  return (unsigned short)(u>>16);
}
__device__ __forceinline__ short8 pack8(const float* f){
  short8 s;
#pragma unroll
  for(int i=0;i<8;i++) s[i] = (short)f2b(f[i]);
  return s;
}

// grid barrier, cheap form:
//  - arrive: RMW. RELEASE (one wbl2) only if this block produced data this stage.
//  - spin: RELAXED agent-scope loads (coherent read-through, NO per-poll invalidate).
//  - one acquire fence per block after the flag trips.
__device__ __forceinline__ void gsync(unsigned target, bool wrote){
  __syncthreads();                 // drains vmcnt -> block stores are in L2
  if(threadIdx.x==0){
    if(wrote)
      __hip_atomic_fetch_add(&g_cnt, 1u, __ATOMIC_RELEASE, __HIP_MEMORY_SCOPE_AGENT);
    else
      __hip_atomic_fetch_add(&g_cnt, 1u, __ATOMIC_RELAXED, __HIP_MEMORY_SCOPE_AGENT);
    while(__hip_atomic_load(&g_cnt, __ATOMIC_RELAXED, __HIP_MEMORY_SCOPE_AGENT) < target){
      __builtin_amdgcn_s_sleep(2);
    }
  }
  __syncthreads();
  __builtin_amdgcn_fence(__ATOMIC_ACQUIRE, "agent");   // single inv, after release point
}

// ---------------- shared-memory union (one allocation reused by every stage) ----------
struct SmemG { unsigned short As[64][72]; unsigned short Bs[128][72];
               float mu[64]; float rs[64]; };                                     // 28.2 KB
struct SmemA { float kv[SEQ][DHEAD]; float wsm[32][132]; float qs[32][68]; };     // 58.4 KB
struct SmemC { float raw[DMODEL]; float ctx[DMODEL]; float scr[4]; };             //  4.1 KB
struct SmemR { float cur[DIN]; float gs[DFFN]; float dscr[DIN]; };                //  8.4 KB
union alignas(16) SmemU { SmemG g; SmemA a; SmemC c; SmemR r; };

// ---------------- one-time: convert all weights to bf16 ----------------
__global__ __launch_bounds__(256) void conv_w(const float* __restrict__ Wq,
                                              const float* __restrict__ Wk,
                                              const float* __restrict__ Wv,
                                              const float* __restrict__ Wo,
                                              const float* __restrict__ W1,
                                              const float* __restrict__ W2,
                                              unsigned short* __restrict__ dst){
  size_t base = ((size_t)blockIdx.x*256 + threadIdx.x)*8;
  if(base >= 12582912u) return;
  const float* src; size_t off;
  if(base < 1048576u){ src=Wq; off=base; }
  else if(base < 2097152u){ src=Wk; off=base-1048576u; }
  else if(base < 3145728u){ src=Wv; off=base-2097152u; }
  else if(base < 4194304u){ src=Wo; off=base-3145728u; }
  else if(base < 8388608u){ src=W1; off=base-4194304u; }
  else { src=W2; off=base-8388608u; }
  float4 a = *(const float4*)(src+off);
  float4 b = *(const float4*)(src+off+4);
  float f[8] = {a.x,a.y,a.z,a.w,b.x,b.y,b.z,b.w};
  *(short8*)(dst + base) = pack8(f);
}

// ---------------- h0 init (fp32 + bf16) ----------------
__global__ __launch_bounds__(256) void init_h0(const float* __restrict__ hist,
                                               const float* __restrict__ W_emb,
                                               const float* __restrict__ b_emb,
                                               float* __restrict__ h0,
                                               unsigned short* __restrict__ h0b){
  int bt = blockIdx.x;
  int b = bt >> 7, t = bt & 127;
  __shared__ float x[DIN];
  if(threadIdx.x < DIN)
    x[threadIdx.x] = (t < TH_) ? hist[((size_t)b*TH_ + t)*DIN + threadIdx.x] : 0.f;
  __syncthreads();
  for(int d = threadIdx.x; d < DMODEL; d += 256){
    float s = 0.f;
#pragma unroll 8
    for(int i=0;i<DIN;i++) s += W_emb[d*DIN+i]*x[i];
    float v = SCALE_EMB*(s + b_emb[d]) + pe_val(t,d);
    h0[(size_t)bt*DMODEL + d] = v;
    h0b[(size_t)bt*DMODEL + d] = f2b(v);
  }
}

// ---------------- M1 / cb1 / cur_x init (+ barrier reset) ----------------
__global__ __launch_bounds__(256) void init_misc(const float* __restrict__ Wr1,
                                                 const float* __restrict__ W_emb,
                                                 const float* __restrict__ b_emb,
                                                 const float* __restrict__ br1,
                                                 const float* __restrict__ hist,
                                                 float* __restrict__ M1,
                                                 float* __restrict__ cb1,
                                                 float* __restrict__ cur_x){
  if(blockIdx.x==0 && threadIdx.x==255) g_cnt = 0u;   // reset grid barrier each replay
  __shared__ float row[DMODEL];
  int j0 = blockIdx.x*8;
  for(int jj=0;jj<8;jj++){
    int j = j0+jj;
    for(int k=threadIdx.x;k<DMODEL;k+=256) row[k] = Wr1[(size_t)j*1024 + k];
    __syncthreads();
    if(threadIdx.x < DIN){
      int i = threadIdx.x; float s = 0.f;
      for(int k=0;k<DMODEL;k++) s += row[k]*W_emb[k*DIN+i];
      M1[j*DIN+i] = SCALE_EMB*s;
    } else if(threadIdx.x == DIN){
      float s=0.f;
      for(int k=0;k<DMODEL;k++) s += row[k]*b_emb[k];
      cb1[j] = br1[j] + SCALE_EMB*s;
    }
    __syncthreads();
  }
  if(blockIdx.x==0 && threadIdx.x<NB*DIN){
    int b = threadIdx.x>>5, i = threadIdx.x&31;
    cur_x[b*DIN+i] = hist[((size_t)b*TH_ + (TH_-1))*DIN + i];
  }
}

// ---------------- bf16 MFMA GEMM tile 64x128, 4 waves, with optional fused LN ----------
// ln_mode: 0 = none
//          1 = A operand is LN(lnx)*lng+lnbta, packed bf16 on the fly (A16 unused)
//          2 = residual added in epilogue is LN(lnx)*lng+lnbta (resid ptr unused)
// LN row stats are computed with the exact wave-per-row reduction of the old lnpass
// kernel (lane l sums its 8 floats, then shfl_xor tree) -> bit-identical mu/rs.
__device__ __forceinline__ void gemm_body(int bx, int by, SmemG& S,
    const unsigned short* __restrict__ A16, int Ka,
    const unsigned short* __restrict__ Wa,
    const unsigned short* __restrict__ Wb,
    const unsigned short* __restrict__ Wc,
    const float* __restrict__ bias, const float* __restrict__ resid,
    const float* __restrict__ lnx, const float* __restrict__ lng,
    const float* __restrict__ lnbta, int ln_mode,
    float* __restrict__ Cf, unsigned short* __restrict__ Cb,
    int c_rs, int c_mode, int act)
{
  int n0 = bx*128;
  int m0 = by*64;
  int tid = threadIdx.x, w = tid>>6, ln = tid&63;

  const unsigned short* Wsrc; int nrow0;
  if(c_mode==2){ int which = n0>>9; Wsrc = (which==0?Wa:(which==1?Wb:Wc)); nrow0 = n0&511; }
  else { Wsrc = Wa; nrow0 = n0; }

  // ---- LN row-stats prologue (rows m0..m0+63 of lnx, stride DMODEL) ----
  if(ln_mode){
    int l = tid&63;
#pragma unroll 1
    for(int rr=0;rr<16;rr++){
      int r = w*16 + rr;
      const float* xp = lnx + (size_t)(m0+r)*DMODEL + l*8;
      float4 x0 = *(const float4*)xp;
      float4 x1 = *(const float4*)(xp+4);
      float f[8] = {x0.x,x0.y,x0.z,x0.w,x1.x,x1.y,x1.z,x1.w};
      float s = 0.f;
#pragma unroll
      for(int i=0;i<8;i++) s += f[i];
      s = wave_sum(s);
      float mu = s*(1.f/DMODEL);
      float v = 0.f;
#pragma unroll
      for(int i=0;i<8;i++){ float d0=f[i]-mu; v += d0*d0; }
      v = wave_sum(v);
      float rsv = rsqrtf(v*(1.f/DMODEL) + LN_EPS);
      if(l==0){ S.mu[r]=mu; S.rs[r]=rsv; }
    }
    __syncthreads();
  }

  f32x4 acc[4][2];
#pragma unroll
  for(int i=0;i<4;i++)
#pragma unroll
    for(int j=0;j<2;j++) acc[i][j] = (f32x4){0.f,0.f,0.f,0.f};

  int fr = ln&15, fq = (ln>>4)*8;
  int arow = tid>>2, akq = (tid&3)*16;
  int brow = tid>>1, bkq = (tid&1)*32;

  float amu=0.f, ars=0.f;
  if(ln_mode==1){ amu = S.mu[arow]; ars = S.rs[arow]; }

  for(int k0=0;k0<Ka;k0+=64){
    if(ln_mode==1){
      const float* fp = lnx + (size_t)(m0+arow)*DMODEL + k0 + akq;
      const float* gp = lng + k0 + akq;
      const float* cp = lnbta + k0 + akq;
#pragma unroll
      for(int h=0;h<2;h++){
        float4 q0 = *(const float4*)(fp+8*h);
        float4 q1 = *(const float4*)(fp+8*h+4);
        float4 g0 = *(const float4*)(gp+8*h);
        float4 g1 = *(const float4*)(gp+8*h+4);
        float4 c0 = *(const float4*)(cp+8*h);
        float4 c1 = *(const float4*)(cp+8*h+4);
        float t[8]  = {q0.x,q0.y,q0.z,q0.w,q1.x,q1.y,q1.z,q1.w};
        float gg[8] = {g0.x,g0.y,g0.z,g0.w,g1.x,g1.y,g1.z,g1.w};
        float cc[8] = {c0.x,c0.y,c0.z,c0.w,c1.x,c1.y,c1.z,c1.w};
        float o[8];
#pragma unroll
        for(int i=0;i<8;i++) o[i] = (t[i]-amu)*ars*gg[i] + cc[i];
        *(short8*)&S.As[arow][akq+8*h] = pack8(o);
      }
    } else {
      const unsigned short* ap = A16 + (size_t)(m0+arow)*Ka + k0 + akq;
      short8 a0 = *(const short8*)ap;
      short8 a1 = *(const short8*)(ap+8);
      *(short8*)&S.As[arow][akq]   = a0;
      *(short8*)&S.As[arow][akq+8] = a1;
    }
    const unsigned short* bp = Wsrc + (size_t)(nrow0+brow)*Ka + k0 + bkq;
    short8 b0 = *(const short8*)bp;
    short8 b1 = *(const short8*)(bp+8);
    short8 b2 = *(const short8*)(bp+16);
    short8 b3 = *(const short8*)(bp+24);
    *(short8*)&S.Bs[brow][bkq]    = b0;
    *(short8*)&S.Bs[brow][bkq+8]  = b1;
    *(short8*)&S.Bs[brow][bkq+16] = b2;
    *(short8*)&S.Bs[brow][bkq+24] = b3;
    __syncthreads();
    short8 af[4][2], bf[2][2];
#pragma unroll
    for(int kf=0;kf<2;kf++){
#pragma unroll
      for(int rt=0;rt<4;rt++) af[rt][kf] = *(const short8*)&S.As[rt*16 + fr][kf*32 + fq];
#pragma unroll
      for(int ct=0;ct<2;ct++) bf[ct][kf] = *(const short8*)&S.Bs[32*w + ct*16 + fr][kf*32 + fq];
    }
#pragma unroll
    for(int kf=0;kf<2;kf++)
#pragma unroll
      for(int rt=0;rt<4;rt++)
#pragma unroll
        for(int ct=0;ct<2;ct++)
          acc[rt][ct] = __builtin_amdgcn_mfma_f32_16x16x32_bf16(af[rt][kf], bf[ct][kf], acc[rt][ct], 0, 0, 0);
    __syncthreads();
  }

#pragma unroll
  for(int rt=0;rt<4;rt++){
#pragma unroll
    for(int ct=0;ct<2;ct++){
      int n = n0 + 32*w + ct*16 + fr;
#pragma unroll
      for(int r=0;r<4;r++){
        int ri = rt*16 + (ln>>4)*4 + r;       // row within tile
        int row = m0 + ri;
        float v = acc[rt][ct][r];
        if(bias)  v += bias[n];
        if(ln_mode==2){
          float x = lnx[(size_t)row*DMODEL + n];
          v += (x - S.mu[ri])*S.rs[ri]*lng[n] + lnbta[n];
        } else if(resid) v += resid[(size_t)row*DMODEL + n];
        if(act==1) v = gelu_t(v);
        if(c_mode==0)      Cf[(size_t)row*c_rs + n] = v;
        else if(c_mode==1) Cb[(size_t)row*c_rs + n] = f2b(v);
        else {
          int which = n>>9, rem = n&511;
          int b = row>>7, t = row&127;
          Cf[(size_t)which*(MROWS*DMODEL) +
             ((size_t)(b*NHEAD + (rem>>6))*SEQ + t)*DHEAD + (rem&63)] = v;
        }
      }
    }
  }
}

// fused attention per (b,h); 32 rows per body call; writes bf16.
__device__ __forceinline__ void attn_body(int bx, int h, int b, SmemA& S,
                                          const float* __restrict__ qb,
                                          const float* __restrict__ kb,
                                          const float* __restrict__ vbuf,
                                          unsigned short* __restrict__ attb){
  int r0 = bx*32;
  const float* Kh = kb   + (size_t)(b*NHEAD+h)*SEQ*DHEAD;
  const float* Vh = vbuf + (size_t)(b*NHEAD+h)*SEQ*DHEAD;
  const float* Qh = qb   + (size_t)(b*NHEAD+h)*SEQ*DHEAD;
  int tid = threadIdx.x;
  int d = tid&63, rr = tid>>6;

  for(int k=rr;k<SEQ;k+=4) S.kv[k][d ^ (k&60)] = Kh[k*DHEAD + d];
  for(int r=rr;r<32;r+=4)  S.qs[r][d] = Qh[(size_t)(r0+r)*DHEAD + d];
  __syncthreads();

  { // logits: 2 rows x 8 keys per thread, float4 LDS reads
    int rp = tid>>4;
    int kg = tid&15;
    float acc[2][8];
#pragma unroll
    for(int i=0;i<2;i++)
#pragma unroll
      for(int kk=0;kk<8;kk++) acc[i][kk]=0.f;
#pragma unroll 4
    for(int d4=0;d4<16;d4++){
      float4 q0 = *(const float4*)&S.qs[2*rp][d4*4];
      float4 q1 = *(const float4*)&S.qs[2*rp+1][d4*4];
#pragma unroll
      for(int kk=0;kk<8;kk++){
        int k = 8*kg + kk;
        int off = (d4*4) ^ (k&60);
        float4 kv4 = *(const float4*)&S.kv[k][off];
        acc[0][kk] += q0.x*kv4.x + q0.y*kv4.y + q0.z*kv4.z + q0.w*kv4.w;
        acc[1][kk] += q1.x*kv4.x + q1.y*kv4.y + q1.z*kv4.z + q1.w*kv4.w;
      }
    }
#pragma unroll
    for(int i=0;i<2;i++){
      int t = r0 + 2*rp + i;
#pragma unroll
      for(int kk=0;kk<8;kk++){
        int k = 8*kg + kk;
        S.wsm[2*rp+i][k] = (k > t) ? acc[i][kk]*0.125f : NEGF;
      }
    }
  }
  __syncthreads();

  { // softmax per row (all-masked row -> uniform 1/128, faithful to jnp)
    int l2 = tid&63, wv = tid>>6;
    for(int r=wv;r<32;r+=4){
      float l0 = S.wsm[r][l2], l1 = S.wsm[r][l2+64];
      float m = fmaxf(l0,l1);
#pragma unroll
      for(int off=32;off;off>>=1) m = fmaxf(m, __shfl_xor(m,off,64));
      float e0 = expf(l0-m), e1 = expf(l1-m);
      float s = e0+e1;
      s = wave_sum(s);
      float inv = 1.f/s;
      S.wsm[r][l2] = e0*inv; S.wsm[r][l2+64] = e1*inv;
    }
  }
  __syncthreads();

  for(int k=rr;k<SEQ;k+=4) S.kv[k][d] = Vh[k*DHEAD + d];   // overwrite with V
  __syncthreads();

  { // out = w @ V, pack bf16
    int dq = (tid&15)*4, rg = tid>>4;
    for(int r=rg;r<32;r+=16){
      float4 acc2 = make_float4(0.f,0.f,0.f,0.f);
      for(int k=0;k<SEQ;k++){
        float w0 = S.wsm[r][k];
        float4 v = *(const float4*)&S.kv[k][dq];
        acc2.x += w0*v.x; acc2.y += w0*v.y; acc2.z += w0*v.z; acc2.w += w0*v.w;
      }
      int row = b*SEQ + r0 + r;
      unsigned short* op = attb + (size_t)row*DMODEL + h*DHEAD + dq;
      op[0]=f2b(acc2.x); op[1]=f2b(acc2.y); op[2]=f2b(acc2.z); op[3]=f2b(acc2.w);
    }
  }
}

// ctx = LN2_3(r2[ptr-1]); ctxt = Wr1b@ctx + cb1
__device__ __forceinline__ void ctx_body(int jx, int b, SmemC& S,
                                         const float* __restrict__ r2,
                                         const float* __restrict__ g2,
                                         const float* __restrict__ b2,
                                         const float* __restrict__ Wr1,
                                         const float* __restrict__ cb1,
                                         float* __restrict__ ctxt, int ptr){
  int j0 = jx*128;
  int tid = threadIdx.x;
  const float* rp = r2 + (size_t)(b*SEQ + ptr-1)*DMODEL;
  for(int k=tid;k<DMODEL;k+=256) S.raw[k]=rp[k];
  __syncthreads();
  float s = 0.f;
  for(int k=tid;k<DMODEL;k+=256) s += S.raw[k];
  s = blk_sum(s, S.scr);
  float mu = s/(float)DMODEL;
  float v = 0.f;
  for(int k=tid;k<DMODEL;k+=256){ float d0 = S.raw[k]-mu; v += d0*d0; }
  v = blk_sum(v, S.scr);
  float rs = rsqrtf(v/(float)DMODEL + LN_EPS);
  for(int k=tid;k<DMODEL;k+=256) S.ctx[k] = (S.raw[k]-mu)*rs*g2[k] + b2[k];
  __syncthreads();
  int wv = tid>>6, l2 = tid&63;
  for(int jj=wv;jj<128;jj+=4){
    int j = j0+jj;
    const float* wp = Wr1 + (size_t)j*1024 + 512;
    float acc = 0.f;
#pragma unroll
    for(int q=0;q<8;q++){ int k = l2 + 64*q; acc += wp[k]*S.ctx[k]; }
    acc = wave_sum(acc);
    if(l2==0) ctxt[b*DFFN + j] = acc + cb1[j];
  }
}

// fused refine (5 substeps) + finalize; one body call per batch.
__device__ __forceinline__ void refine_body(int b, SmemR& S,
                                            const float* __restrict__ M1,
                                            const float* __restrict__ ctxt,
                                            const float* __restrict__ Wr2,
                                            const float* __restrict__ br2,
                                            float* __restrict__ cur_x,
                                            const float* __restrict__ W_emb,
                                            const float* __restrict__ b_emb,
                                            float* __restrict__ out,
                                            float* __restrict__ h0,
                                            unsigned short* __restrict__ h0b,
                                            int s, int ptr){
  int tid = threadIdx.x;
  if(tid < DIN) S.cur[tid] = cur_x[b*DIN + tid];
  __syncthreads();
  for(int sub=0; sub<5; sub++){
    for(int jj=tid; jj<DFFN; jj+=256){
      float u = ctxt[b*DFFN + jj];
      const float* mp = M1 + (size_t)jj*DIN;
#pragma unroll
      for(int p=0;p<8;p++){
        float4 mv = *(const float4*)(mp + 4*p);
        u += mv.x*S.cur[4*p] + mv.y*S.cur[4*p+1] + mv.z*S.cur[4*p+2] + mv.w*S.cur[4*p+3];
      }
      S.gs[jj] = gelu_t(u);
    }
    __syncthreads();
    int w = tid>>6, l = tid&63;
#pragma unroll
    for(int q=0;q<8;q++){
      int i = w*8 + q;
      const float* wr = Wr2 + (size_t)i*DFFN;
      float a = 0.f;
#pragma unroll
      for(int p=0;p<8;p++){
        int j0 = p*256 + l*4;
        float4 wv = *(const float4*)(wr + j0);
        float4 gv = *(const float4*)&S.gs[j0];
        a += wv.x*gv.x + wv.y*gv.y + wv.z*gv.z + wv.w*gv.w;
      }
      a = wave_sum(a);
      if(l==0) S.dscr[i] = a;
    }
    __syncthreads();
    if(tid < DIN) S.cur[tid] += S.dscr[tid] + br2[tid];
    __syncthreads();
  }
  if(tid < DIN){
    out[(b*NSTEP + s)*DIN + tid] = S.cur[tid];
    cur_x[b*DIN + tid] = S.cur[tid];
  }
  __syncthreads();
  for(int d=tid; d<DMODEL; d+=256){
    float s2 = 0.f;
#pragma unroll 8
    for(int i=0;i<DIN;i++) s2 += W_emb[d*DIN+i]*S.cur[i];
    float v = SCALE_EMB*(s2 + b_emb[d]) + pe_val(ptr, d);
    size_t idx = (size_t)(b*SEQ + ptr)*DMODEL + d;
    h0[idx] = v;
    h0b[idx] = f2b(v);
  }
}

// ---------------- megakernel params ----------------
struct MegaP {
  const float *ln1g, *ln1b, *b1, *b2v, *ln2g, *ln2b, *Wr1, *W_emb, *b_emb, *Wr2, *br2;
  float *out;
  float *h0; unsigned short *h0b;
  float *r2, *r1;                       // r1 = old hp buffer (pre-LN1 residual input)
  float *qb, *kb, *vb; unsigned short *attb, *fbuf16;
  const unsigned short *Wq16, *Wk16, *Wv16, *Wo16, *W116, *W216;
  float *M1, *cb1, *ctxt, *cur_x;
};

// ---------------- persistent megakernel: 22 barriers/step (LN fused into GEMMs) --------
__global__ __launch_bounds__(256,1) void mega(MegaP p){
  __shared__ SmemU sm;
  const unsigned vbk = blockIdx.x;
  unsigned ep = 0;
#define GS(wrote) do{ ++ep; gsync(ep*NBLK, (wrote)); }while(0)

  for(int s=0;s<NSTEP;s++){
    int ptr = TH_ + s;
    for(int l=0;l<4;l++){
      const float* g2p = p.ln2g + (l-1)*DMODEL;   // only valid when l>0
      const float* b2p = p.ln2b + (l-1)*DMODEL;
      const float* g1p = p.ln1g + l*DMODEL;
      const float* b1p = p.ln1b + l*DMODEL;

      // ---- QKV (A = l==0 ? h0b : LN2(r2) fused); N=1536 scatter -> qb/kb/vb ----
      if(vbk < 96){
        int bx = (int)(vbk%12u), by = (int)(vbk/12u);
        if(l==0)
          gemm_body(bx, by, sm.g, p.h0b, DMODEL,
                    p.Wq16 + (size_t)l*262144, p.Wk16 + (size_t)l*262144, p.Wv16 + (size_t)l*262144,
                    nullptr, nullptr, nullptr, nullptr, nullptr, 0,
                    p.qb, nullptr, 0, 2, 0);
        else
          gemm_body(bx, by, sm.g, nullptr, DMODEL,
                    p.Wq16 + (size_t)l*262144, p.Wk16 + (size_t)l*262144, p.Wv16 + (size_t)l*262144,
                    nullptr, nullptr, p.r2, g2p, b2p, 1,
                    p.qb, nullptr, 0, 2, 0);
      }
      GS(vbk<96);

      // ---- attention (128 blocks) ----
      attn_body((int)(vbk&3u), (int)((vbk>>2)&7u), (int)(vbk>>5), sm.a, p.qb, p.kb, p.vb, p.attb);
      GS(true);

      // ---- Wo: att@Wo^T + (l==0 ? h0 : LN2(r2)) -> r1 fp32 (32 blocks) ----
      if(vbk < 32){
        int bx = (int)(vbk&3u), by = (int)(vbk>>2);
        if(l==0)
          gemm_body(bx, by, sm.g, p.attb, DMODEL,
                    p.Wo16 + (size_t)l*262144, nullptr, nullptr,
                    nullptr, p.h0, nullptr, nullptr, nullptr, 0,
                    p.r1, nullptr, DMODEL, 0, 0);
        else
          gemm_body(bx, by, sm.g, p.attb, DMODEL,
                    p.Wo16 + (size_t)l*262144, nullptr, nullptr,
                    nullptr, nullptr, p.r2, g2p, b2p, 2,
                    p.r1, nullptr, DMODEL, 0, 0);
      }
      GS(vbk<32);

      // ---- FF1: gelu(LN1(r1)@W1^T + b1) -> fbuf bf16 (128 blocks) ----
      gemm_body((int)(vbk&15u), (int)(vbk>>4), sm.g, nullptr, DMODEL,
                p.W116 + (size_t)l*1048576, nullptr, nullptr,
                p.b1 + l*DFFN, nullptr, p.r1, g1p, b1p, 1,
                nullptr, p.fbuf16, DFFN, 1, 1);
      GS(true);

      // ---- FF2: fbuf@W2^T + b2 + LN1(r1) -> r2 fp32 (32 blocks) ----
      if(vbk < 32)
        gemm_body((int)(vbk&3u), (int)(vbk>>2), sm.g, p.fbuf16, DFFN,
                  p.W216 + (size_t)l*1048576, nullptr, nullptr,
                  p.b2v + l*DMODEL, nullptr, p.r1, g1p, b1p, 2,
                  p.r2, nullptr, DMODEL, 0, 0);
      GS(vbk<32);
    }

    // ---- ctx (64 blocks) ----
    if(vbk < 64)
      ctx_body((int)(vbk&15u), (int)(vbk>>4), sm.c, p.r2,
               p.ln2g + 3*DMODEL, p.ln2b + 3*DMODEL, p.Wr1, p.cb1, p.ctxt, ptr);
    GS(vbk<64);

    // ---- refine + finalize + write next h0 row (4 blocks) ----
    if(vbk < 4)
      refine_body((int)vbk, sm.r, p.M1, p.ctxt, p.Wr2, p.br2, p.cur_x,
                  p.W_emb, p.b_emb, p.out, p.h0, p.h0b, s, ptr);
    GS(vbk<4);
  }
#undef GS
}

// ---------------- host ----------------
extern "C" void kernel_launch(void* const* d_in, const int* in_sizes, int n_in,
                              void* d_out, int out_size, void* d_ws, size_t ws_size,
                              hipStream_t stream) {
  (void)in_sizes; (void)n_in; (void)out_size; (void)ws_size;
  const float* hist = (const float*)d_in[0];
  const float* W_emb= (const float*)d_in[2];
  const float* b_emb= (const float*)d_in[3];
  const float* Wq   = (const float*)d_in[4];
  const float* Wk   = (const float*)d_in[5];
  const float* Wv   = (const float*)d_in[6];
  const float* Wo   = (const float*)d_in[7];
  const float* ln1g = (const float*)d_in[8];
  const float* ln1b = (const float*)d_in[9];
  const float* W1   = (const float*)d_in[10];
  const float* b1   = (const float*)d_in[11];
  const float* W2   = (const float*)d_in[12];
  const float* b2v  = (const float*)d_in[13];
  const float* ln2g = (const float*)d_in[14];
  const float* ln2b = (const float*)d_in[15];
  const float* Wr1  = (const float*)d_in[16];
  const float* br1  = (const float*)d_in[17];
  const float* Wr2  = (const float*)d_in[18];
  const float* br2  = (const float*)d_in[19];
  float* out = (float*)d_out;
  float* ws  = (float*)d_ws;

  const size_t BTD = (size_t)MROWS*DMODEL;      // 262144 floats
  const size_t BTDH = BTD/2;                    // bf16 buffer in float units
  float* h0   = ws;
  unsigned short* h0b = (unsigned short*)(h0 + BTD);
  float* r2   = h0 + BTD + BTDH;
  float* hln  = r2 + BTD;                       // dead (kept for layout compat)
  float* hp   = hln + BTD;                      // reused as r1 (pre-LN1 residual)
  float* qb   = hp + BTD + BTDH;
  float* kb   = qb + BTD;
  float* vb   = kb + BTD;
  unsigned short* attb = (unsigned short*)(vb + BTD);
  unsigned short* fbuf16 = (unsigned short*)qb;   // [512][2048] bf16 (over qb/kb, dead then)
  unsigned short* W16 = (unsigned short*)(qb + 4*BTD);
  float* after_w = qb + 4*BTD + 6291456;
  float* M1   = after_w;
  float* cb1  = M1 + (size_t)DFFN*DIN;
  float* ctxt = cb1 + DFFN;
  float* cur_x= ctxt + NB*DFFN;

  unsigned short* Wq16 = W16;
  unsigned short* Wk16 = W16 + 1048576;
  unsigned short* Wv16 = W16 + 2097152;
  unsigned short* Wo16 = W16 + 3145728;
  unsigned short* W116 = W16 + 4194304;
  unsigned short* W216 = W16 + 8388608;

  conv_w<<<dim3(6144),dim3(256),0,stream>>>(Wq,Wk,Wv,Wo,W1,W2,W16);
  init_h0<<<dim3(MROWS),dim3(256),0,stream>>>(hist,W_emb,b_emb,h0,h0b);
  init_misc<<<dim3(256),dim3(256),0,stream>>>(Wr1,W_emb,b_emb,br1,hist,M1,cb1,cur_x);

  MegaP p;
  p.ln1g=ln1g; p.ln1b=ln1b; p.b1=b1; p.b2v=b2v; p.ln2g=ln2g; p.ln2b=ln2b;
  p.Wr1=Wr1; p.W_emb=W_emb; p.b_emb=b_emb; p.Wr2=Wr2; p.br2=br2;
  p.out=out;
  p.h0=h0; p.h0b=h0b;
  p.r2=r2; p.r1=hp;
  p.qb=qb; p.kb=kb; p.vb=vb; p.attb=attb; p.fbuf16=fbuf16;
  p.Wq16=Wq16; p.Wk16=Wk16; p.Wv16=Wv16; p.Wo16=Wo16; p.W116=W116; p.W216=W216;
  p.M1=M1; p.cb1=cb1; p.ctxt=ctxt; p.cur_x=cur_x;

  mega<<<dim3(NBLK),dim3(256),0,stream>>>(p);
}